// Round 14
// baseline (654.406 us; speedup 1.0000x reference)
//
#include <hip/hip_runtime.h>
#include <stdint.h>

#define N_CL 40000
#define NF   20
#define DD   128
#define SS   512
#define NW   625                 // N_CL / 64
#define PARTN (NW * SS)
#define NEGF (-3.0e38f)
#define DISCOUNT 0.995f
#define ECOEF 0.1f

typedef __attribute__((ext_vector_type(4))) float f32x4;
typedef __attribute__((ext_vector_type(16))) float f32x16;
typedef __attribute__((ext_vector_type(8))) short short8;
typedef __attribute__((ext_vector_type(4))) unsigned short us4;

__device__ __forceinline__ float rcpf(float x) { return __builtin_amdgcn_rcpf(x); }
__device__ __forceinline__ float sigm(float x) { return rcpf(1.f + __expf(-x)); }
__device__ __forceinline__ float tanh_fast(float x) { return 1.f - 2.f * rcpf(1.f + __expf(2.f * x)); }
__device__ __forceinline__ unsigned short f2bf(float f) {
    unsigned u = __float_as_uint(f);
    return (unsigned short)((u + 0x7fffu + ((u >> 16) & 1u)) >> 16);   // RNE
}
__device__ __forceinline__ float bf2f(unsigned short s) {
    return __uint_as_float(((unsigned)s) << 16);
}

// ------- FUSED hidden+emb: emb = relu(feat@W1+b1)@W2+b2, bf16 hi/lo out --------
#define EMB_FMA(RR) { f32x4 hvv = *(const f32x4*)&hs[rg * 8 + RR][q]; \
    acc##RR += wv0 * hvv.x + wv1 * hvv.y + wv2 * hvv.z + wv3 * hvv.w; }
#define EMB_ST(RR) { f32x4 f = acc##RR + bv; us4 hi, lo; \
    hi[0] = f2bf(f.x); lo[0] = f2bf(f.x - bf2f(hi[0])); \
    hi[1] = f2bf(f.y); lo[1] = f2bf(f.y - bf2f(hi[1])); \
    hi[2] = f2bf(f.z); lo[2] = f2bf(f.z - bf2f(hi[2])); \
    hi[3] = f2bf(f.w); lo[3] = f2bf(f.w - bf2f(hi[3])); \
    int row_ = rbase + rg * 8 + RR; \
    *(us4*)&emb_hi[row_ * DD + c4 * 4] = hi; \
    *(us4*)&emb_lo[row_ * DD + c4 * 4] = lo; }

__global__ __launch_bounds__(256) void k_emb(const float* __restrict__ feat,
                                             const float* __restrict__ W1,
                                             const float* __restrict__ b1,
                                             const float* __restrict__ W2,
                                             const float* __restrict__ b2,
                                             unsigned short* __restrict__ emb_hi,
                                             unsigned short* __restrict__ emb_lo) {
    __shared__ float fs[64][NF];                      // 5.1 KB feat tile
    __shared__ float hs[64][132];                     // +4 pad, 33.8 KB
    int t = threadIdx.x;
    int rbase = blockIdx.x * 64;
    for (int i = t; i < 64 * NF; i += 256)
        fs[i / NF][i % NF] = feat[rbase * NF + i];
    __syncthreads();
    {   // hidden tile: 64 rows x 128 cols = 8192 elems, 32 per thread.
        int c = t & 127;
        float bb = b1[c];
#pragma unroll
        for (int k = 0; k < 32; ++k) {
            int r = (t >> 7) + 2 * k;
            float acc = bb;
#pragma unroll
            for (int f = 0; f < NF; ++f) acc += fs[r][f] * W1[f * DD + c];
            hs[r][c] = fmaxf(acc, 0.f);
        }
    }
    __syncthreads();
    int c4 = t & 31, rg = t >> 5;
    f32x4 acc0{0,0,0,0}, acc1{0,0,0,0}, acc2{0,0,0,0}, acc3{0,0,0,0},
          acc4{0,0,0,0}, acc5{0,0,0,0}, acc6{0,0,0,0}, acc7{0,0,0,0};
    for (int q = 0; q < DD; q += 4) {
        f32x4 wv0 = *(const f32x4*)&W2[(q + 0) * DD + c4 * 4];
        f32x4 wv1 = *(const f32x4*)&W2[(q + 1) * DD + c4 * 4];
        f32x4 wv2 = *(const f32x4*)&W2[(q + 2) * DD + c4 * 4];
        f32x4 wv3 = *(const f32x4*)&W2[(q + 3) * DD + c4 * 4];
        EMB_FMA(0) EMB_FMA(1) EMB_FMA(2) EMB_FMA(3)
        EMB_FMA(4) EMB_FMA(5) EMB_FMA(6) EMB_FMA(7)
    }
    f32x4 bv = *(const f32x4*)&b2[c4 * 4];
    EMB_ST(0) EMB_ST(1) EMB_ST(2) EMB_ST(3)
    EMB_ST(4) EMB_ST(5) EMB_ST(6) EMB_ST(7)
}

// ---- P2[s][pos][g] = bih[j]+bhh[j]+Wih[j].emb[sel_idx[s]],  j=g*128+pos ------
// blocks 64..95: one-time Whh pre-transpose into W2T (coalesced k_lstm layout):
// W2T chunk cid=(w*32+(r*8+q))*64+l  <-  Whh[row=(w>>2)*256+l*4+r][col=(w&3)*32+q*4]
__global__ __launch_bounds__(256) void k_pgemm(const unsigned short* __restrict__ emb_hi,
                                               const unsigned short* __restrict__ emb_lo,
                                               const int* __restrict__ sel_idx,
                                               const float* __restrict__ Wih,
                                               const float* __restrict__ bih,
                                               const float* __restrict__ bhh,
                                               const float* __restrict__ Whh,
                                               float* __restrict__ W2T,
                                               float* __restrict__ P2) {
    if (blockIdx.x >= 64) {
        int tid = (blockIdx.x - 64) * 256 + threadIdx.x;   // 0..8191
#pragma unroll
        for (int k = 0; k < 2; ++k) {
            int cid = tid * 2 + k;                         // 0..16383
            int w = cid >> 11;
            int i = (cid >> 6) & 31;
            int l = cid & 63;
            int r = i >> 3, q = i & 7;
            int row = (w >> 2) * 256 + l * 4 + r;
            int col = (w & 3) * 32 + q * 4;
            *(f32x4*)&W2T[cid * 4] = *(const f32x4*)&Whh[row * DD + col];
        }
        return;
    }
    __shared__ __align__(16) float x8[8][DD];
    int t = threadIdx.x;
    int sb = blockIdx.x * 8;
    for (int i = t; i < 8 * DD; i += 256) {
        int sl = i >> 7, k = i & 127;
        int idx = sel_idx[sb + sl] * DD + k;
        x8[sl][k] = bf2f(emb_hi[idx]) + bf2f(emb_lo[idx]);
    }
    __syncthreads();
    for (int jj = t; jj < 512; jj += 256) {
        float base = bih[jj] + bhh[jj];
        float acc[8];
#pragma unroll
        for (int s8 = 0; s8 < 8; ++s8) acc[s8] = base;
        const float4* wr = (const float4*)(Wih + jj * DD);
        for (int q = 0; q < 32; ++q) {
            float4 w4 = wr[q];
#pragma unroll
            for (int s8 = 0; s8 < 8; ++s8) {
                const float4* xs = (const float4*)&x8[s8][0];
                float4 xv = xs[q];
                acc[s8] += w4.x * xv.x + w4.y * xv.y + w4.z * xv.z + w4.w * xv.w;
            }
        }
        int pos = jj & 127, g = jj >> 7;
        for (int s8 = 0; s8 < 8; ++s8) P2[(sb + s8) * 512 + pos * 4 + g] = acc[s8];
    }
}

// ------- sequential LSTM scan: r13 + asm-LAUNDERED resident weights ------------
// r13 autopsy: waves_per_eu(2,2) applied (SGPR 32->112) but VGPR stayed 96 --
// the per-step asm barrier's "memory" clobber invalidates the W2T loads, and
// reloading is free in the allocator's model, so it remats every step (64
// load-inst/SIMD/step + exposed L2 latency = the ~800cyc gap vs issue model).
// Fix needs BOTH: budget (waves_per_eu(2,2), r13) AND launder (empty asm
// "+v" makes weights outputs of an opaque asm -- NOT rematerializable, immune
// to the memory clobber). r4 had launder w/o budget; r13 budget w/o launder.
#define MQ(Q) { f32x4 hv = hp[Q]; \
    a0 += w0##Q * hv; a1 += w1##Q * hv; a2 += w2##Q * hv; a3 += w3##Q * hv; }

#define STEP(J, PV) { \
    const f32x4* hp = (const f32x4*)&h_w[w][0]; \
    f32x4 a0{0,0,0,0}, a1{0,0,0,0}, a2{0,0,0,0}, a3{0,0,0,0}; \
    MQ(0) MQ(1) MQ(2) MQ(3) MQ(4) MQ(5) MQ(6) MQ(7) \
    f32x4 ps; \
    ps.x = (a0.x + a0.y) + (a0.z + a0.w); \
    ps.y = (a1.x + a1.y) + (a1.z + a1.w); \
    ps.z = (a2.x + a2.y) + (a2.z + a2.w); \
    ps.w = (a3.x + a3.y) + (a3.z + a3.w); \
    *(f32x4*)&psum[(J) & 1][kq][gbase] = ps; \
    asm volatile("s_waitcnt lgkmcnt(0)\n\ts_barrier" ::: "memory"); \
    if ((J) == 0 && gh == 1 && g8 > 0) {                 /* bulk H store, prev group */ \
        int pg_ = (g8 - 1) & 1; \
        _Pragma("unroll") \
        for (int u_ = 0; u_ < 2; ++u_) { \
            int jj_ = 2 * (w - 4) + u_, sp_ = (g8 - 1) * 8 + jj_; \
            float2 hv_ = *(const float2*)&h_hist[pg_][jj_][2 * l]; \
            unsigned short ah_ = f2bf(hv_.x), bh_ = f2bf(hv_.y); \
            unsigned short al_ = f2bf(hv_.x - bf2f(ah_)), bl_ = f2bf(hv_.y - bf2f(bh_)); \
            *(unsigned*)&Hhi[sp_ * DD + 2 * l] = (unsigned)ah_ | ((unsigned)bh_ << 16); \
            *(unsigned*)&Hlo[sp_ * DD + 2 * l] = (unsigned)al_ | ((unsigned)bl_ << 16); \
        } \
    } \
    float q00 = psum[(J) & 1][0][t_el],       q01 = psum[(J) & 1][1][t_el]; \
    float q02 = psum[(J) & 1][2][t_el],       q03 = psum[(J) & 1][3][t_el]; \
    float q10 = psum[(J) & 1][0][128 + t_el], q11 = psum[(J) & 1][1][128 + t_el]; \
    float q12 = psum[(J) & 1][2][128 + t_el], q13 = psum[(J) & 1][3][128 + t_el]; \
    float q20 = psum[(J) & 1][0][256 + t_el], q21 = psum[(J) & 1][1][256 + t_el]; \
    float q22 = psum[(J) & 1][2][256 + t_el], q23 = psum[(J) & 1][3][256 + t_el]; \
    float q30 = psum[(J) & 1][0][384 + t_el], q31 = psum[(J) & 1][1][384 + t_el]; \
    float q32 = psum[(J) & 1][2][384 + t_el], q33 = psum[(J) & 1][3][384 + t_el]; \
    float gi = ((q00 + q01) + (q02 + q03)) + (PV).x; \
    float gf = ((q10 + q11) + (q12 + q13)) + (PV).y; \
    float gg = ((q20 + q21) + (q22 + q23)) + (PV).z; \
    float go = ((q30 + q31) + (q32 + q33)) + (PV).w; \
    float ii = sigm(gi), ff = sigm(gf), tg = tanh_fast(gg), oo = sigm(go); \
    c = ff * c + ii * tg; \
    float hh = oo * tanh_fast(c); \
    if (l < 32) { \
        h_w[w][ln] = hh; \
        if (gh == 0) h_hist[(g8 + (((J) == 7) ? 1 : 0)) & 1][((J) + 1) & 7][t_el] = hh; \
    } \
}

__global__ __launch_bounds__(512)
__attribute__((amdgpu_waves_per_eu(2, 2)))
void k_lstm(const float* __restrict__ W2T,
            const float* __restrict__ P2,
            const float* __restrict__ init_h,
            const float* __restrict__ init_c,
            unsigned short* __restrict__ Hhi,
            unsigned short* __restrict__ Hlo,
            const int* __restrict__ sel,
            const int* __restrict__ good,
            unsigned long long* __restrict__ selw,
            unsigned long long* __restrict__ goodw) {
    if (blockIdx.x != 0) {
        // ---- mask pack path: ballot -> u64 words, TRANSPOSED layout [b][s] ----
        int wave = ((blockIdx.x - 1) * 512 + threadIdx.x) >> 6;   // 0..4999
        int lane = threadIdx.x & 63;
        for (int i = 0; i < 64; ++i) {
            int chunk = wave * 64 + i;                  // 0..319999
            int s = chunk / NW;
            int b = chunk - s * NW;
            int idx = s * N_CL + b * 64 + lane;
            unsigned long long bs = __ballot(sel[idx]  != 0);
            unsigned long long bg = __ballot(good[idx] != 0);
            if (lane == 0) { selw[b * SS + s] = bs; goodw[b * SS + s] = bg; }
        }
        return;
    }

    __shared__ __align__(16) float psum[2][4][512];   // 16 KB, parity dbuf
    __shared__ __align__(16) float h_w[8][32];        // 1 KB, wave-private h
    __shared__ __align__(16) float h_hist[2][8][128]; // 8 KB, H history (parity)

    int t = threadIdx.x, w = t >> 6, l = t & 63;
    int kq = w & 3, gh = w >> 2, ln = l & 31;
    int gbase = gh * 256 + l * 4;
    int t_el = kq * 32 + ln;

    // coalesced weight base: wave w, lane l; instruction i at wT[i*64]
    const f32x4* wT = (const f32x4*)W2T + (size_t)w * 2048 + l;
    f32x4 w00 = wT[ 0 * 64], w01 = wT[ 1 * 64], w02 = wT[ 2 * 64], w03 = wT[ 3 * 64],
          w04 = wT[ 4 * 64], w05 = wT[ 5 * 64], w06 = wT[ 6 * 64], w07 = wT[ 7 * 64];
    f32x4 w10 = wT[ 8 * 64], w11 = wT[ 9 * 64], w12 = wT[10 * 64], w13 = wT[11 * 64],
          w14 = wT[12 * 64], w15 = wT[13 * 64], w16 = wT[14 * 64], w17 = wT[15 * 64];
    f32x4 w20 = wT[16 * 64], w21 = wT[17 * 64], w22 = wT[18 * 64], w23 = wT[19 * 64],
          w24 = wT[20 * 64], w25 = wT[21 * 64], w26 = wT[22 * 64], w27 = wT[23 * 64];
    f32x4 w30 = wT[24 * 64], w31 = wT[25 * 64], w32 = wT[26 * 64], w33 = wT[27 * 64],
          w34 = wT[28 * 64], w35 = wT[29 * 64], w36 = wT[30 * 64], w37 = wT[31 * 64];
    // LAUNDER: weights become opaque asm outputs -> not rematerializable from
    // memory, so the per-step barrier's "memory" clobber cannot force reloads.
    asm volatile("" : "+v"(w00), "+v"(w01), "+v"(w02), "+v"(w03),
                      "+v"(w04), "+v"(w05), "+v"(w06), "+v"(w07));
    asm volatile("" : "+v"(w10), "+v"(w11), "+v"(w12), "+v"(w13),
                      "+v"(w14), "+v"(w15), "+v"(w16), "+v"(w17));
    asm volatile("" : "+v"(w20), "+v"(w21), "+v"(w22), "+v"(w23),
                      "+v"(w24), "+v"(w25), "+v"(w26), "+v"(w27));
    asm volatile("" : "+v"(w30), "+v"(w31), "+v"(w32), "+v"(w33),
                      "+v"(w34), "+v"(w35), "+v"(w36), "+v"(w37));

    float c = init_c[t_el];                           // dup across lane halves
    if (l < 32) {
        float h0 = init_h[t_el];
        h_w[w][ln] = h0;
        if (gh == 0) h_hist[0][0][t_el] = h0;         // h input of step 0
    }
    asm volatile("s_waitcnt lgkmcnt(0)\n\ts_barrier" ::: "memory");

    for (int g8 = 0; g8 < 64; ++g8) {
        const float* pb = P2 + g8 * 4096 + t_el * 4;  // this thread's gate slice
        f32x4 pv0 = *(const f32x4*)(pb + 0 * 512);
        f32x4 pv1 = *(const f32x4*)(pb + 1 * 512);
        f32x4 pv2 = *(const f32x4*)(pb + 2 * 512);
        f32x4 pv3 = *(const f32x4*)(pb + 3 * 512);
        STEP(0, pv0) STEP(1, pv1) STEP(2, pv2) STEP(3, pv3)
        f32x4 pv4 = *(const f32x4*)(pb + 4 * 512);
        f32x4 pv5 = *(const f32x4*)(pb + 5 * 512);
        f32x4 pv6 = *(const f32x4*)(pb + 6 * 512);
        f32x4 pv7 = *(const f32x4*)(pb + 7 * 512);
        STEP(4, pv4) STEP(5, pv5) STEP(6, pv6) STEP(7, pv7)
    }

    // tail: store group 63's H (steps 504..511), parity 1
    asm volatile("s_waitcnt lgkmcnt(0)\n\ts_barrier" ::: "memory");
    if (gh == 1) {
#pragma unroll
        for (int u = 0; u < 2; ++u) {
            int jj = 2 * (w - 4) + u, sp = 504 + jj;
            float2 hv = *(const float2*)&h_hist[1][jj][2 * l];
            unsigned short ah = f2bf(hv.x), bh = f2bf(hv.y);
            unsigned short al = f2bf(hv.x - bf2f(ah)), bl = f2bf(hv.y - bf2f(bh));
            *(unsigned*)&Hhi[sp * DD + 2 * l] = (unsigned)ah | ((unsigned)bh << 16);
            *(unsigned*)&Hlo[sp * DD + 2 * l] = (unsigned)al | ((unsigned)bl << 16);
        }
    }
}

// ------- phase C: MFMA GEMM logits, SINGLE PASS over all 512 steps -------------
__global__ __launch_bounds__(256, 1) void k_logits(
        const unsigned short* __restrict__ emb_hi,
        const unsigned short* __restrict__ emb_lo,
        const unsigned short* __restrict__ Hhi,
        const unsigned short* __restrict__ Hlo,
        const unsigned long long* __restrict__ selw,
        const unsigned long long* __restrict__ goodw,
        float* __restrict__ part) {
    int b = blockIdx.x;
    int t = threadIdx.x, wv = t >> 6, l = t & 63;
    int ln = l & 31, lh = l >> 5;
    int rb = b * 64;
    const short8* A0h = (const short8*)(emb_hi + (rb + ln) * DD + lh * 8);
    const short8* A0l = (const short8*)(emb_lo + (rb + ln) * DD + lh * 8);
    const short8* A1h = (const short8*)(emb_hi + (rb + 32 + ln) * DD + lh * 8);
    const short8* A1l = (const short8*)(emb_lo + (rb + 32 + ln) * DD + lh * 8);
    for (int sg = 0; sg < 4; ++sg) {
        int s0 = sg * 128 + wv * 32;
        const short8* Bhp = (const short8*)(Hhi + (s0 + ln) * DD + lh * 8);
        const short8* Blp = (const short8*)(Hlo + (s0 + ln) * DD + lh * 8);
        f32x16 acc0, acc1;
#pragma unroll
        for (int r = 0; r < 16; ++r) { acc0[r] = 0.f; acc1[r] = 0.f; }
#pragma unroll
        for (int kc = 0; kc < 8; ++kc) {           // K = 8 x 16
            short8 a0h = A0h[kc * 2], a0l = A0l[kc * 2];
            short8 a1h = A1h[kc * 2], a1l = A1l[kc * 2];
            short8 bh = Bhp[kc * 2], bl = Blp[kc * 2];
            acc0 = __builtin_amdgcn_mfma_f32_32x32x16_bf16(a0h, bh, acc0, 0, 0, 0);
            acc0 = __builtin_amdgcn_mfma_f32_32x32x16_bf16(a0l, bh, acc0, 0, 0, 0);
            acc0 = __builtin_amdgcn_mfma_f32_32x32x16_bf16(a0h, bl, acc0, 0, 0, 0);
            acc1 = __builtin_amdgcn_mfma_f32_32x32x16_bf16(a1h, bh, acc1, 0, 0, 0);
            acc1 = __builtin_amdgcn_mfma_f32_32x32x16_bf16(a1l, bh, acc1, 0, 0, 0);
            acc1 = __builtin_amdgcn_mfma_f32_32x32x16_bf16(a1h, bl, acc1, 0, 0, 0);
        }
        int s = s0 + ln;
        unsigned long long sw = selw[b * SS + s];  // coalesced, [b][s] layout
        unsigned long long gw = goodw[b * SS + s];
        float m = NEGF;
#pragma unroll
        for (int r = 0; r < 16; ++r) {
            int row = (r & 3) + 8 * (r >> 2) + 4 * lh;
            float v0 = acc0[r], v1 = acc1[r];
            m = fmaxf(m, ((sw >> row) & 1ull) ? v0 : NEGF);
            m = fmaxf(m, ((sw >> (row + 32)) & 1ull) ? v1 : NEGF);
        }
        m = fmaxf(m, __shfl_xor(m, 32));
        float se = 0.f, sl = 0.f, slg = 0.f;
#pragma unroll
        for (int r = 0; r < 16; ++r) {
            int row = (r & 3) + 8 * (r >> 2) + 4 * lh;
            float v0 = acc0[r], v1 = acc1[r];
            float e0 = ((sw >> row) & 1ull) ? __expf(v0 - m) : 0.f;
            float e1 = ((sw >> (row + 32)) & 1ull) ? __expf(v1 - m) : 0.f;
            se += e0 + e1;
            sl += e0 * v0 + e1 * v1;
            slg += (((gw >> row) & 1ull) ? v0 : 0.f)
                 + (((gw >> (row + 32)) & 1ull) ? v1 : 0.f);
        }
        se += __shfl_xor(se, 32);
        sl += __shfl_xor(sl, 32);
        slg += __shfl_xor(slg, 32);
        if (lh == 0) {
            int o = s * NW + b;                    // TRANSPOSED part: [s][b]
            part[0 * PARTN + o] = m;
            part[1 * PARTN + o] = se;
            part[2 * PARTN + o] = sl;
            part[3 * PARTN + o] = slg;
            part[4 * PARTN + o] = (float)__popcll(sw);
            part[5 * PARTN + o] = (float)__popcll(gw);
        }
    }
}

// ------- per-step merge of 625 block partials (coalesced [s][b] reads) ---------
__global__ __launch_bounds__(64) void k_reduce(const float* __restrict__ part,
                                               float* __restrict__ Aout,
                                               float* __restrict__ Bout,
                                               float* __restrict__ actout) {
    int s = blockIdx.x;
    int t = threadIdx.x;     // 64 threads, one wave
    float m = NEGF, se = 0.f, sl = 0.f, slg = 0.f, np = 0.f, ng = 0.f;
    for (int b = t; b < NW; b += 64) {
        int o = s * NW + b;                        // lanes consecutive
        float m2  = part[0 * PARTN + o];
        float se2 = part[1 * PARTN + o];
        float sl2 = part[2 * PARTN + o];
        slg += part[3 * PARTN + o];
        np  += part[4 * PARTN + o];
        ng  += part[5 * PARTN + o];
        float nm = fmaxf(m, m2);
        float a = __expf(m - nm), a2 = __expf(m2 - nm);
        se = se * a + se2 * a2;
        sl = sl * a + sl2 * a2;
        m = nm;
    }
    for (int off = 32; off > 0; off >>= 1) {
        float m2  = __shfl_xor(m, off);
        float se2 = __shfl_xor(se, off);
        float sl2 = __shfl_xor(sl, off);
        slg += __shfl_xor(slg, off);
        np  += __shfl_xor(np, off);
        ng  += __shfl_xor(ng, off);
        float nm = fmaxf(m, m2);
        float a = __expf(m - nm), a2 = __expf(m2 - nm);
        se = se * a + se2 * a2;
        sl = sl * a + sl2 * a2;
        m = nm;
    }
    if (t == 0) {
        float lse = m + logf(se);
        float nbad = np - ng;
        int active = (ng > 0.5f) && (nbad > 0.5f);
        float ce = (ng * lse - slg) / fmaxf(ng, 1.f);
        float A = (nbad / fmaxf(np, 1.f)) * ce;
        float minus_ent = sl / se - lse;
        float B = ECOEF * (minus_ent / logf(fmaxf(np, 2.0f)));
        Aout[s] = A; Bout[s] = B; actout[s] = active ? 1.f : 0.f;
    }
}

// ---------------- exact sequential discount prefix + final sum -----------------
__global__ __launch_bounds__(64) void k_final(const float* __restrict__ A,
                                              const float* __restrict__ B,
                                              const float* __restrict__ act,
                                              float* __restrict__ out) {
    int lane = threadIdx.x;
    float loss = 0.f;
    int base = 0;
    for (int ch = 0; ch < 8; ++ch) {
        int s = ch * 64 + lane;
        bool a = act[s] > 0.5f;
        unsigned long long bal = __ballot(a);
        unsigned long long ltmask = (lane == 0) ? 0ull : (~0ull >> (64 - lane));
        int pre = __popcll(bal & ltmask);
        if (a) {
            float f = powf(DISCOUNT, (float)(base + pre));
            loss += f * A[s] + B[s];
        }
        base += __popcll(bal);
    }
    for (int off = 32; off > 0; off >>= 1) loss += __shfl_xor(loss, off);
    if (lane == 0) out[0] = loss / fmaxf((float)base, 1.f);
}

extern "C" void kernel_launch(void* const* d_in, const int* in_sizes, int n_in,
                              void* d_out, int out_size, void* d_ws, size_t ws_size,
                              hipStream_t stream) {
    (void)in_sizes; (void)n_in; (void)out_size; (void)ws_size;
    const float* feat    = (const float*)d_in[0];
    const int*   sel     = (const int*)d_in[1];
    const int*   good    = (const int*)d_in[2];
    const int*   sel_idx = (const int*)d_in[3];
    const float* W1      = (const float*)d_in[4];
    const float* b1      = (const float*)d_in[5];
    const float* W2      = (const float*)d_in[6];
    const float* b2      = (const float*)d_in[7];
    const float* init_h  = (const float*)d_in[8];
    const float* init_c  = (const float*)d_in[9];
    const float* Wih     = (const float*)d_in[10];
    const float* Whh     = (const float*)d_in[11];
    const float* bih     = (const float*)d_in[12];
    const float* bhh     = (const float*)d_in[13];
    float* out = (float*)d_out;
    char* ws = (char*)d_ws;

    float*          W2T    = (float*)(ws + 0);                    //  1,048,576 B
    unsigned short* emb_hi = (unsigned short*)(ws + 20480000);    // 10,240,000 B
    unsigned short* emb_lo = (unsigned short*)(ws + 30720000);    // 10,240,000 B
    float*          P2     = (float*)(ws + 40960000);             //  1,048,576 B
    unsigned short* Hhi    = (unsigned short*)(ws + 42008576);    //    131,072 B
    unsigned short* Hlo    = (unsigned short*)(ws + 42139648);    //    131,072 B
    unsigned long long* selw  = (unsigned long long*)(ws + 42270720);  // 2,560,000 B
    unsigned long long* goodw = (unsigned long long*)(ws + 44830720);  // 2,560,000 B
    float*          part   = (float*)(ws + 47390720);             //  7,680,000 B
    float*          Aarr   = (float*)(ws + 55070720);             //      2,048 B
    float*          Barr   = (float*)(ws + 55072768);             //      2,048 B
    float*          actarr = (float*)(ws + 55074816);             //      2,048 B

    k_emb   <<<NW, 256, 0, stream>>>(feat, W1, b1, W2, b2, emb_hi, emb_lo);
    // blocks 0..63: P2 gemm; blocks 64..95: one-time Whh -> W2T transpose
    k_pgemm <<<96, 256, 0, stream>>>(emb_hi, emb_lo, sel_idx, Wih, bih, bhh,
                                     Whh, W2T, P2);
    // fused: block 0 = serial LSTM scan (1 CU); blocks 1..625 = mask pack on
    // the otherwise-idle CUs (independent work, no inter-block dependency).
    k_lstm  <<<626, 512, 0, stream>>>(W2T, P2, init_h, init_c, Hhi, Hlo,
                                      sel, good, selw, goodw);
    k_logits<<<NW, 256, 0, stream>>>(emb_hi, emb_lo, Hhi, Hlo, selw, goodw, part);
    k_reduce<<<SS, 64, 0, stream>>>(part, Aarr, Barr, actarr);
    k_final <<<1, 64, 0, stream>>>(Aarr, Barr, actarr, out);
}

// Round 15
// 651.845 us; speedup vs baseline: 1.0039x; 1.0039x over previous
//
#include <hip/hip_runtime.h>
#include <stdint.h>

#define N_CL 40000
#define NF   20
#define DD   128
#define SS   512
#define NW   625                 // N_CL / 64
#define PARTN (NW * SS)
#define NEGF (-3.0e38f)
#define DISCOUNT 0.995f
#define ECOEF 0.1f

typedef __attribute__((ext_vector_type(2))) float f32x2;
typedef __attribute__((ext_vector_type(4))) float f32x4;
typedef __attribute__((ext_vector_type(16))) float f32x16;
typedef __attribute__((ext_vector_type(8))) short short8;
typedef __attribute__((ext_vector_type(4))) unsigned short us4;

__device__ __forceinline__ float rcpf(float x) { return __builtin_amdgcn_rcpf(x); }
__device__ __forceinline__ float sigm(float x) { return rcpf(1.f + __expf(-x)); }
__device__ __forceinline__ float tanh_fast(float x) { return 1.f - 2.f * rcpf(1.f + __expf(2.f * x)); }
__device__ __forceinline__ unsigned short f2bf(float f) {
    unsigned u = __float_as_uint(f);
    return (unsigned short)((u + 0x7fffu + ((u >> 16) & 1u)) >> 16);   // RNE
}
__device__ __forceinline__ float bf2f(unsigned short s) {
    return __uint_as_float(((unsigned)s) << 16);
}

// ------- FUSED hidden+emb: emb = relu(feat@W1+b1)@W2+b2, bf16 hi/lo out --------
#define EMB_FMA(RR) { f32x4 hvv = *(const f32x4*)&hs[rg * 8 + RR][q]; \
    acc##RR += wv0 * hvv.x + wv1 * hvv.y + wv2 * hvv.z + wv3 * hvv.w; }
#define EMB_ST(RR) { f32x4 f = acc##RR + bv; us4 hi, lo; \
    hi[0] = f2bf(f.x); lo[0] = f2bf(f.x - bf2f(hi[0])); \
    hi[1] = f2bf(f.y); lo[1] = f2bf(f.y - bf2f(hi[1])); \
    hi[2] = f2bf(f.z); lo[2] = f2bf(f.z - bf2f(hi[2])); \
    hi[3] = f2bf(f.w); lo[3] = f2bf(f.w - bf2f(hi[3])); \
    int row_ = rbase + rg * 8 + RR; \
    *(us4*)&emb_hi[row_ * DD + c4 * 4] = hi; \
    *(us4*)&emb_lo[row_ * DD + c4 * 4] = lo; }

__global__ __launch_bounds__(256) void k_emb(const float* __restrict__ feat,
                                             const float* __restrict__ W1,
                                             const float* __restrict__ b1,
                                             const float* __restrict__ W2,
                                             const float* __restrict__ b2,
                                             unsigned short* __restrict__ emb_hi,
                                             unsigned short* __restrict__ emb_lo) {
    __shared__ float fs[64][NF];                      // 5.1 KB feat tile
    __shared__ float hs[64][132];                     // +4 pad, 33.8 KB
    int t = threadIdx.x;
    int rbase = blockIdx.x * 64;
    for (int i = t; i < 64 * NF; i += 256)
        fs[i / NF][i % NF] = feat[rbase * NF + i];
    __syncthreads();
    {   // hidden tile: 64 rows x 128 cols = 8192 elems, 32 per thread.
        int c = t & 127;
        float bb = b1[c];
#pragma unroll
        for (int k = 0; k < 32; ++k) {
            int r = (t >> 7) + 2 * k;
            float acc = bb;
#pragma unroll
            for (int f = 0; f < NF; ++f) acc += fs[r][f] * W1[f * DD + c];
            hs[r][c] = fmaxf(acc, 0.f);
        }
    }
    __syncthreads();
    int c4 = t & 31, rg = t >> 5;
    f32x4 acc0{0,0,0,0}, acc1{0,0,0,0}, acc2{0,0,0,0}, acc3{0,0,0,0},
          acc4{0,0,0,0}, acc5{0,0,0,0}, acc6{0,0,0,0}, acc7{0,0,0,0};
    for (int q = 0; q < DD; q += 4) {
        f32x4 wv0 = *(const f32x4*)&W2[(q + 0) * DD + c4 * 4];
        f32x4 wv1 = *(const f32x4*)&W2[(q + 1) * DD + c4 * 4];
        f32x4 wv2 = *(const f32x4*)&W2[(q + 2) * DD + c4 * 4];
        f32x4 wv3 = *(const f32x4*)&W2[(q + 3) * DD + c4 * 4];
        EMB_FMA(0) EMB_FMA(1) EMB_FMA(2) EMB_FMA(3)
        EMB_FMA(4) EMB_FMA(5) EMB_FMA(6) EMB_FMA(7)
    }
    f32x4 bv = *(const f32x4*)&b2[c4 * 4];
    EMB_ST(0) EMB_ST(1) EMB_ST(2) EMB_ST(3)
    EMB_ST(4) EMB_ST(5) EMB_ST(6) EMB_ST(7)
}

// ---- P2[s][pos][g] = bih[j]+bhh[j]+Wih[j].emb[sel_idx[s]],  j=g*128+pos ------
// blocks 64..95: one-time Whh pre-transpose into W2T (coalesced k_lstm layout):
// W2T chunk cid=(w*32+(r*8+q))*64+l  <-  Whh[row=(w>>2)*256+l*4+r][col=(w&3)*32+q*4]
__global__ __launch_bounds__(256) void k_pgemm(const unsigned short* __restrict__ emb_hi,
                                               const unsigned short* __restrict__ emb_lo,
                                               const int* __restrict__ sel_idx,
                                               const float* __restrict__ Wih,
                                               const float* __restrict__ bih,
                                               const float* __restrict__ bhh,
                                               const float* __restrict__ Whh,
                                               float* __restrict__ W2T,
                                               float* __restrict__ P2) {
    if (blockIdx.x >= 64) {
        int tid = (blockIdx.x - 64) * 256 + threadIdx.x;   // 0..8191
#pragma unroll
        for (int k = 0; k < 2; ++k) {
            int cid = tid * 2 + k;                         // 0..16383
            int w = cid >> 11;
            int i = (cid >> 6) & 31;
            int l = cid & 63;
            int r = i >> 3, q = i & 7;
            int row = (w >> 2) * 256 + l * 4 + r;
            int col = (w & 3) * 32 + q * 4;
            *(f32x4*)&W2T[cid * 4] = *(const f32x4*)&Whh[row * DD + col];
        }
        return;
    }
    __shared__ __align__(16) float x8[8][DD];
    int t = threadIdx.x;
    int sb = blockIdx.x * 8;
    for (int i = t; i < 8 * DD; i += 256) {
        int sl = i >> 7, k = i & 127;
        int idx = sel_idx[sb + sl] * DD + k;
        x8[sl][k] = bf2f(emb_hi[idx]) + bf2f(emb_lo[idx]);
    }
    __syncthreads();
    for (int jj = t; jj < 512; jj += 256) {
        float base = bih[jj] + bhh[jj];
        float acc[8];
#pragma unroll
        for (int s8 = 0; s8 < 8; ++s8) acc[s8] = base;
        const float4* wr = (const float4*)(Wih + jj * DD);
        for (int q = 0; q < 32; ++q) {
            float4 w4 = wr[q];
#pragma unroll
            for (int s8 = 0; s8 < 8; ++s8) {
                const float4* xs = (const float4*)&x8[s8][0];
                float4 xv = xs[q];
                acc[s8] += w4.x * xv.x + w4.y * xv.y + w4.z * xv.z + w4.w * xv.w;
            }
        }
        int pos = jj & 127, g = jj >> 7;
        for (int s8 = 0; s8 < 8; ++s8) P2[(sb + s8) * 512 + pos * 4 + g] = acc[s8];
    }
}

// ------- sequential LSTM scan: r11 base + f32x2 matvec (packed-FMA eligible) ---
// Six weight-path variants (r1/r4/r11/r12/r13/r14) all measured 359-377 us ->
// weight fetch is NOT the limiter. The one halvable arithmetic floor is FMA
// issue: 65536 FMA/step at 128 FMA/cyc/CU (plain f32) = 512 cyc; v_pk_fma_f32
// doubles to 256 FMA/cyc. Express the matvec on f32x2 vectors with PLAIN C
// ops (hipcc -ffp-contract=fast -> packed fma ISel), keeping the compiler's
// scheduling freedom (r7's inline-asm version serialized loads and lost 10x).
// Reduction order preserved exactly: a0l={k0,k1},a0h={k2,k3};
// ps.x=(a0l.x+a0l.y)+(a0h.x+a0h.y) == old (a0.x+a0.y)+(a0.z+a0.w) -> absmax 0.
#define LO2(V) __builtin_shufflevector(V, V, 0, 1)
#define HI2(V) __builtin_shufflevector(V, V, 2, 3)
#define MQ(Q) { f32x4 hv = hp[Q]; \
    f32x2 hl = LO2(hv), hh2 = HI2(hv); \
    a0l += LO2(w0##Q) * hl; a0h += HI2(w0##Q) * hh2; \
    a1l += LO2(w1##Q) * hl; a1h += HI2(w1##Q) * hh2; \
    a2l += LO2(w2##Q) * hl; a2h += HI2(w2##Q) * hh2; \
    a3l += LO2(w3##Q) * hl; a3h += HI2(w3##Q) * hh2; }

#define STEP(J, PV) { \
    const f32x4* hp = (const f32x4*)&h_w[w][0]; \
    f32x2 a0l{0,0}, a0h{0,0}, a1l{0,0}, a1h{0,0}, \
          a2l{0,0}, a2h{0,0}, a3l{0,0}, a3h{0,0}; \
    MQ(0) MQ(1) MQ(2) MQ(3) MQ(4) MQ(5) MQ(6) MQ(7) \
    f32x4 ps; \
    ps.x = (a0l.x + a0l.y) + (a0h.x + a0h.y); \
    ps.y = (a1l.x + a1l.y) + (a1h.x + a1h.y); \
    ps.z = (a2l.x + a2l.y) + (a2h.x + a2h.y); \
    ps.w = (a3l.x + a3l.y) + (a3h.x + a3h.y); \
    *(f32x4*)&psum[(J) & 1][kq][gbase] = ps; \
    asm volatile("s_waitcnt lgkmcnt(0)\n\ts_barrier" ::: "memory"); \
    if ((J) == 0 && gh == 1 && g8 > 0) {                 /* bulk H store, prev group */ \
        int pg_ = (g8 - 1) & 1; \
        _Pragma("unroll") \
        for (int u_ = 0; u_ < 2; ++u_) { \
            int jj_ = 2 * (w - 4) + u_, sp_ = (g8 - 1) * 8 + jj_; \
            float2 hv_ = *(const float2*)&h_hist[pg_][jj_][2 * l]; \
            unsigned short ah_ = f2bf(hv_.x), bh_ = f2bf(hv_.y); \
            unsigned short al_ = f2bf(hv_.x - bf2f(ah_)), bl_ = f2bf(hv_.y - bf2f(bh_)); \
            *(unsigned*)&Hhi[sp_ * DD + 2 * l] = (unsigned)ah_ | ((unsigned)bh_ << 16); \
            *(unsigned*)&Hlo[sp_ * DD + 2 * l] = (unsigned)al_ | ((unsigned)bl_ << 16); \
        } \
    } \
    float q00 = psum[(J) & 1][0][t_el],       q01 = psum[(J) & 1][1][t_el]; \
    float q02 = psum[(J) & 1][2][t_el],       q03 = psum[(J) & 1][3][t_el]; \
    float q10 = psum[(J) & 1][0][128 + t_el], q11 = psum[(J) & 1][1][128 + t_el]; \
    float q12 = psum[(J) & 1][2][128 + t_el], q13 = psum[(J) & 1][3][128 + t_el]; \
    float q20 = psum[(J) & 1][0][256 + t_el], q21 = psum[(J) & 1][1][256 + t_el]; \
    float q22 = psum[(J) & 1][2][256 + t_el], q23 = psum[(J) & 1][3][256 + t_el]; \
    float q30 = psum[(J) & 1][0][384 + t_el], q31 = psum[(J) & 1][1][384 + t_el]; \
    float q32 = psum[(J) & 1][2][384 + t_el], q33 = psum[(J) & 1][3][384 + t_el]; \
    float gi = ((q00 + q01) + (q02 + q03)) + (PV).x; \
    float gf = ((q10 + q11) + (q12 + q13)) + (PV).y; \
    float gg = ((q20 + q21) + (q22 + q23)) + (PV).z; \
    float go = ((q30 + q31) + (q32 + q33)) + (PV).w; \
    float ii = sigm(gi), ff = sigm(gf), tg = tanh_fast(gg), oo = sigm(go); \
    c = ff * c + ii * tg; \
    float hh = oo * tanh_fast(c); \
    if (l < 32) { \
        h_w[w][ln] = hh; \
        if (gh == 0) h_hist[(g8 + (((J) == 7) ? 1 : 0)) & 1][((J) + 1) & 7][t_el] = hh; \
    } \
}

__global__ __launch_bounds__(512, 1) void k_lstm(const float* __restrict__ W2T,
                                                 const float* __restrict__ P2,
                                                 const float* __restrict__ init_h,
                                                 const float* __restrict__ init_c,
                                                 unsigned short* __restrict__ Hhi,
                                                 unsigned short* __restrict__ Hlo,
                                                 const int* __restrict__ sel,
                                                 const int* __restrict__ good,
                                                 unsigned long long* __restrict__ selw,
                                                 unsigned long long* __restrict__ goodw) {
    if (blockIdx.x != 0) {
        // ---- mask pack path: ballot -> u64 words, TRANSPOSED layout [b][s] ----
        int wave = ((blockIdx.x - 1) * 512 + threadIdx.x) >> 6;   // 0..4999
        int lane = threadIdx.x & 63;
        for (int i = 0; i < 64; ++i) {
            int chunk = wave * 64 + i;                  // 0..319999
            int s = chunk / NW;
            int b = chunk - s * NW;
            int idx = s * N_CL + b * 64 + lane;
            unsigned long long bs = __ballot(sel[idx]  != 0);
            unsigned long long bg = __ballot(good[idx] != 0);
            if (lane == 0) { selw[b * SS + s] = bs; goodw[b * SS + s] = bg; }
        }
        return;
    }

    __shared__ __align__(16) float psum[2][4][512];   // 16 KB, parity dbuf
    __shared__ __align__(16) float h_w[8][32];        // 1 KB, wave-private h
    __shared__ __align__(16) float h_hist[2][8][128]; // 8 KB, H history (parity)

    int t = threadIdx.x, w = t >> 6, l = t & 63;
    int kq = w & 3, gh = w >> 2, ln = l & 31;
    int gbase = gh * 256 + l * 4;
    int t_el = kq * 32 + ln;

    // coalesced weight base: wave w, lane l; instruction i at wT[i*64]
    const f32x4* wT = (const f32x4*)W2T + (size_t)w * 2048 + l;
    f32x4 w00 = wT[ 0 * 64], w01 = wT[ 1 * 64], w02 = wT[ 2 * 64], w03 = wT[ 3 * 64],
          w04 = wT[ 4 * 64], w05 = wT[ 5 * 64], w06 = wT[ 6 * 64], w07 = wT[ 7 * 64];
    f32x4 w10 = wT[ 8 * 64], w11 = wT[ 9 * 64], w12 = wT[10 * 64], w13 = wT[11 * 64],
          w14 = wT[12 * 64], w15 = wT[13 * 64], w16 = wT[14 * 64], w17 = wT[15 * 64];
    f32x4 w20 = wT[16 * 64], w21 = wT[17 * 64], w22 = wT[18 * 64], w23 = wT[19 * 64],
          w24 = wT[20 * 64], w25 = wT[21 * 64], w26 = wT[22 * 64], w27 = wT[23 * 64];
    f32x4 w30 = wT[24 * 64], w31 = wT[25 * 64], w32 = wT[26 * 64], w33 = wT[27 * 64],
          w34 = wT[28 * 64], w35 = wT[29 * 64], w36 = wT[30 * 64], w37 = wT[31 * 64];

    float c = init_c[t_el];                           // dup across lane halves
    if (l < 32) {
        float h0 = init_h[t_el];
        h_w[w][ln] = h0;
        if (gh == 0) h_hist[0][0][t_el] = h0;         // h input of step 0
    }
    asm volatile("s_waitcnt lgkmcnt(0)\n\ts_barrier" ::: "memory");

    for (int g8 = 0; g8 < 64; ++g8) {
        const float* pb = P2 + g8 * 4096 + t_el * 4;  // this thread's gate slice
        f32x4 pv0 = *(const f32x4*)(pb + 0 * 512);
        f32x4 pv1 = *(const f32x4*)(pb + 1 * 512);
        f32x4 pv2 = *(const f32x4*)(pb + 2 * 512);
        f32x4 pv3 = *(const f32x4*)(pb + 3 * 512);
        STEP(0, pv0) STEP(1, pv1) STEP(2, pv2) STEP(3, pv3)
        f32x4 pv4 = *(const f32x4*)(pb + 4 * 512);
        f32x4 pv5 = *(const f32x4*)(pb + 5 * 512);
        f32x4 pv6 = *(const f32x4*)(pb + 6 * 512);
        f32x4 pv7 = *(const f32x4*)(pb + 7 * 512);
        STEP(4, pv4) STEP(5, pv5) STEP(6, pv6) STEP(7, pv7)
    }

    // tail: store group 63's H (steps 504..511), parity 1
    asm volatile("s_waitcnt lgkmcnt(0)\n\ts_barrier" ::: "memory");
    if (gh == 1) {
#pragma unroll
        for (int u = 0; u < 2; ++u) {
            int jj = 2 * (w - 4) + u, sp = 504 + jj;
            float2 hv = *(const float2*)&h_hist[1][jj][2 * l];
            unsigned short ah = f2bf(hv.x), bh = f2bf(hv.y);
            unsigned short al = f2bf(hv.x - bf2f(ah)), bl = f2bf(hv.y - bf2f(bh));
            *(unsigned*)&Hhi[sp * DD + 2 * l] = (unsigned)ah | ((unsigned)bh << 16);
            *(unsigned*)&Hlo[sp * DD + 2 * l] = (unsigned)al | ((unsigned)bl << 16);
        }
    }
}

// ------- phase C: MFMA GEMM logits, SINGLE PASS over all 512 steps -------------
__global__ __launch_bounds__(256, 1) void k_logits(
        const unsigned short* __restrict__ emb_hi,
        const unsigned short* __restrict__ emb_lo,
        const unsigned short* __restrict__ Hhi,
        const unsigned short* __restrict__ Hlo,
        const unsigned long long* __restrict__ selw,
        const unsigned long long* __restrict__ goodw,
        float* __restrict__ part) {
    int b = blockIdx.x;
    int t = threadIdx.x, wv = t >> 6, l = t & 63;
    int ln = l & 31, lh = l >> 5;
    int rb = b * 64;
    const short8* A0h = (const short8*)(emb_hi + (rb + ln) * DD + lh * 8);
    const short8* A0l = (const short8*)(emb_lo + (rb + ln) * DD + lh * 8);
    const short8* A1h = (const short8*)(emb_hi + (rb + 32 + ln) * DD + lh * 8);
    const short8* A1l = (const short8*)(emb_lo + (rb + 32 + ln) * DD + lh * 8);
    for (int sg = 0; sg < 4; ++sg) {
        int s0 = sg * 128 + wv * 32;
        const short8* Bhp = (const short8*)(Hhi + (s0 + ln) * DD + lh * 8);
        const short8* Blp = (const short8*)(Hlo + (s0 + ln) * DD + lh * 8);
        f32x16 acc0, acc1;
#pragma unroll
        for (int r = 0; r < 16; ++r) { acc0[r] = 0.f; acc1[r] = 0.f; }
#pragma unroll
        for (int kc = 0; kc < 8; ++kc) {           // K = 8 x 16
            short8 a0h = A0h[kc * 2], a0l = A0l[kc * 2];
            short8 a1h = A1h[kc * 2], a1l = A1l[kc * 2];
            short8 bh = Bhp[kc * 2], bl = Blp[kc * 2];
            acc0 = __builtin_amdgcn_mfma_f32_32x32x16_bf16(a0h, bh, acc0, 0, 0, 0);
            acc0 = __builtin_amdgcn_mfma_f32_32x32x16_bf16(a0l, bh, acc0, 0, 0, 0);
            acc0 = __builtin_amdgcn_mfma_f32_32x32x16_bf16(a0h, bl, acc0, 0, 0, 0);
            acc1 = __builtin_amdgcn_mfma_f32_32x32x16_bf16(a1h, bh, acc1, 0, 0, 0);
            acc1 = __builtin_amdgcn_mfma_f32_32x32x16_bf16(a1l, bh, acc1, 0, 0, 0);
            acc1 = __builtin_amdgcn_mfma_f32_32x32x16_bf16(a1h, bl, acc1, 0, 0, 0);
        }
        int s = s0 + ln;
        unsigned long long sw = selw[b * SS + s];  // coalesced, [b][s] layout
        unsigned long long gw = goodw[b * SS + s];
        float m = NEGF;
#pragma unroll
        for (int r = 0; r < 16; ++r) {
            int row = (r & 3) + 8 * (r >> 2) + 4 * lh;
            float v0 = acc0[r], v1 = acc1[r];
            m = fmaxf(m, ((sw >> row) & 1ull) ? v0 : NEGF);
            m = fmaxf(m, ((sw >> (row + 32)) & 1ull) ? v1 : NEGF);
        }
        m = fmaxf(m, __shfl_xor(m, 32));
        float se = 0.f, sl = 0.f, slg = 0.f;
#pragma unroll
        for (int r = 0; r < 16; ++r) {
            int row = (r & 3) + 8 * (r >> 2) + 4 * lh;
            float v0 = acc0[r], v1 = acc1[r];
            float e0 = ((sw >> row) & 1ull) ? __expf(v0 - m) : 0.f;
            float e1 = ((sw >> (row + 32)) & 1ull) ? __expf(v1 - m) : 0.f;
            se += e0 + e1;
            sl += e0 * v0 + e1 * v1;
            slg += (((gw >> row) & 1ull) ? v0 : 0.f)
                 + (((gw >> (row + 32)) & 1ull) ? v1 : 0.f);
        }
        se += __shfl_xor(se, 32);
        sl += __shfl_xor(sl, 32);
        slg += __shfl_xor(slg, 32);
        if (lh == 0) {
            int o = s * NW + b;                    // TRANSPOSED part: [s][b]
            part[0 * PARTN + o] = m;
            part[1 * PARTN + o] = se;
            part[2 * PARTN + o] = sl;
            part[3 * PARTN + o] = slg;
            part[4 * PARTN + o] = (float)__popcll(sw);
            part[5 * PARTN + o] = (float)__popcll(gw);
        }
    }
}

// ------- per-step merge of 625 block partials (coalesced [s][b] reads) ---------
__global__ __launch_bounds__(64) void k_reduce(const float* __restrict__ part,
                                               float* __restrict__ Aout,
                                               float* __restrict__ Bout,
                                               float* __restrict__ actout) {
    int s = blockIdx.x;
    int t = threadIdx.x;     // 64 threads, one wave
    float m = NEGF, se = 0.f, sl = 0.f, slg = 0.f, np = 0.f, ng = 0.f;
    for (int b = t; b < NW; b += 64) {
        int o = s * NW + b;                        // lanes consecutive
        float m2  = part[0 * PARTN + o];
        float se2 = part[1 * PARTN + o];
        float sl2 = part[2 * PARTN + o];
        slg += part[3 * PARTN + o];
        np  += part[4 * PARTN + o];
        ng  += part[5 * PARTN + o];
        float nm = fmaxf(m, m2);
        float a = __expf(m - nm), a2 = __expf(m2 - nm);
        se = se * a + se2 * a2;
        sl = sl * a + sl2 * a2;
        m = nm;
    }
    for (int off = 32; off > 0; off >>= 1) {
        float m2  = __shfl_xor(m, off);
        float se2 = __shfl_xor(se, off);
        float sl2 = __shfl_xor(sl, off);
        slg += __shfl_xor(slg, off);
        np  += __shfl_xor(np, off);
        ng  += __shfl_xor(ng, off);
        float nm = fmaxf(m, m2);
        float a = __expf(m - nm), a2 = __expf(m2 - nm);
        se = se * a + se2 * a2;
        sl = sl * a + sl2 * a2;
        m = nm;
    }
    if (t == 0) {
        float lse = m + logf(se);
        float nbad = np - ng;
        int active = (ng > 0.5f) && (nbad > 0.5f);
        float ce = (ng * lse - slg) / fmaxf(ng, 1.f);
        float A = (nbad / fmaxf(np, 1.f)) * ce;
        float minus_ent = sl / se - lse;
        float B = ECOEF * (minus_ent / logf(fmaxf(np, 2.0f)));
        Aout[s] = A; Bout[s] = B; actout[s] = active ? 1.f : 0.f;
    }
}

// ---------------- exact sequential discount prefix + final sum -----------------
__global__ __launch_bounds__(64) void k_final(const float* __restrict__ A,
                                              const float* __restrict__ B,
                                              const float* __restrict__ act,
                                              float* __restrict__ out) {
    int lane = threadIdx.x;
    float loss = 0.f;
    int base = 0;
    for (int ch = 0; ch < 8; ++ch) {
        int s = ch * 64 + lane;
        bool a = act[s] > 0.5f;
        unsigned long long bal = __ballot(a);
        unsigned long long ltmask = (lane == 0) ? 0ull : (~0ull >> (64 - lane));
        int pre = __popcll(bal & ltmask);
        if (a) {
            float f = powf(DISCOUNT, (float)(base + pre));
            loss += f * A[s] + B[s];
        }
        base += __popcll(bal);
    }
    for (int off = 32; off > 0; off >>= 1) loss += __shfl_xor(loss, off);
    if (lane == 0) out[0] = loss / fmaxf((float)base, 1.f);
}

extern "C" void kernel_launch(void* const* d_in, const int* in_sizes, int n_in,
                              void* d_out, int out_size, void* d_ws, size_t ws_size,
                              hipStream_t stream) {
    (void)in_sizes; (void)n_in; (void)out_size; (void)ws_size;
    const float* feat    = (const float*)d_in[0];
    const int*   sel     = (const int*)d_in[1];
    const int*   good    = (const int*)d_in[2];
    const int*   sel_idx = (const int*)d_in[3];
    const float* W1      = (const float*)d_in[4];
    const float* b1      = (const float*)d_in[5];
    const float* W2      = (const float*)d_in[6];
    const float* b2      = (const float*)d_in[7];
    const float* init_h  = (const float*)d_in[8];
    const float* init_c  = (const float*)d_in[9];
    const float* Wih     = (const float*)d_in[10];
    const float* Whh     = (const float*)d_in[11];
    const float* bih     = (const float*)d_in[12];
    const float* bhh     = (const float*)d_in[13];
    float* out = (float*)d_out;
    char* ws = (char*)d_ws;

    float*          W2T    = (float*)(ws + 0);                    //  1,048,576 B
    unsigned short* emb_hi = (unsigned short*)(ws + 20480000);    // 10,240,000 B
    unsigned short* emb_lo = (unsigned short*)(ws + 30720000);    // 10,240,000 B
    float*          P2     = (float*)(ws + 40960000);             //  1,048,576 B
    unsigned short* Hhi    = (unsigned short*)(ws + 42008576);    //    131,072 B
    unsigned short* Hlo    = (unsigned short*)(ws + 42139648);    //    131,072 B
    unsigned long long* selw  = (unsigned long long*)(ws + 42270720);  // 2,560,000 B
    unsigned long long* goodw = (unsigned long long*)(ws + 44830720);  // 2,560,000 B
    float*          part   = (float*)(ws + 47390720);             //  7,680,000 B
    float*          Aarr   = (float*)(ws + 55070720);             //      2,048 B
    float*          Barr   = (float*)(ws + 55072768);             //      2,048 B
    float*          actarr = (float*)(ws + 55074816);             //      2,048 B

    k_emb   <<<NW, 256, 0, stream>>>(feat, W1, b1, W2, b2, emb_hi, emb_lo);
    // blocks 0..63: P2 gemm; blocks 64..95: one-time Whh -> W2T transpose
    k_pgemm <<<96, 256, 0, stream>>>(emb_hi, emb_lo, sel_idx, Wih, bih, bhh,
                                     Whh, W2T, P2);
    // fused: block 0 = serial LSTM scan (1 CU); blocks 1..625 = mask pack on
    // the otherwise-idle CUs (independent work, no inter-block dependency).
    k_lstm  <<<626, 512, 0, stream>>>(W2T, P2, init_h, init_c, Hhi, Hlo,
                                      sel, good, selw, goodw);
    k_logits<<<NW, 256, 0, stream>>>(emb_hi, emb_lo, Hhi, Hlo, selw, goodw, part);
    k_reduce<<<SS, 64, 0, stream>>>(part, Aarr, Barr, actarr);
    k_final <<<1, 64, 0, stream>>>(Aarr, Barr, actarr, out);
}

// Round 16
// 599.432 us; speedup vs baseline: 1.0917x; 1.0874x over previous
//
#include <hip/hip_runtime.h>
#include <stdint.h>

#define N_CL 40000
#define NF   20
#define DD   128
#define SS   512
#define NW   625                 // N_CL / 64
#define PARTN (NW * SS)
#define NEGF (-3.0e38f)
#define DISCOUNT 0.995f
#define ECOEF 0.1f

typedef __attribute__((ext_vector_type(2))) float f32x2;
typedef __attribute__((ext_vector_type(4))) float f32x4;
typedef __attribute__((ext_vector_type(16))) float f32x16;
typedef __attribute__((ext_vector_type(8))) short short8;
typedef __attribute__((ext_vector_type(4))) unsigned short us4;

__device__ __forceinline__ float rcpf(float x) { return __builtin_amdgcn_rcpf(x); }
__device__ __forceinline__ float sigm(float x) { return rcpf(1.f + __expf(-x)); }
__device__ __forceinline__ float tanh_fast(float x) { return 1.f - 2.f * rcpf(1.f + __expf(2.f * x)); }
__device__ __forceinline__ unsigned short f2bf(float f) {
    unsigned u = __float_as_uint(f);
    return (unsigned short)((u + 0x7fffu + ((u >> 16) & 1u)) >> 16);   // RNE
}
__device__ __forceinline__ float bf2f(unsigned short s) {
    return __uint_as_float(((unsigned)s) << 16);
}

// ---- k_pgemm: SELF-CONTAINED — computes its 512 selected-row embeddings
// directly from feat (fp32, more accurate than the old bf16 hi/lo round-trip),
// removing the k_emb dependency so k_lstm can launch right after this tiny
// kernel. blocks 64..95: one-time Whh pre-transpose into W2T.
__global__ __launch_bounds__(256) void k_pgemm(const float* __restrict__ feat,
                                               const float* __restrict__ W1,
                                               const float* __restrict__ b1,
                                               const float* __restrict__ W2,
                                               const float* __restrict__ b2,
                                               const int* __restrict__ sel_idx,
                                               const float* __restrict__ Wih,
                                               const float* __restrict__ bih,
                                               const float* __restrict__ bhh,
                                               const float* __restrict__ Whh,
                                               float* __restrict__ W2T,
                                               float* __restrict__ P2) {
    if (blockIdx.x >= 64) {
        int tid = (blockIdx.x - 64) * 256 + threadIdx.x;   // 0..8191
#pragma unroll
        for (int k = 0; k < 2; ++k) {
            int cid = tid * 2 + k;                         // 0..16383
            int w = cid >> 11;
            int i = (cid >> 6) & 31;
            int l = cid & 63;
            int r = i >> 3, q = i & 7;
            int row = (w >> 2) * 256 + l * 4 + r;
            int col = (w & 3) * 32 + q * 4;
            *(f32x4*)&W2T[cid * 4] = *(const f32x4*)&Whh[row * DD + col];
        }
        return;
    }
    __shared__ __align__(16) float fs2[8][NF];
    __shared__ __align__(16) float hid[8][DD];
    __shared__ __align__(16) float x8[8][DD];
    int t = threadIdx.x;
    int sb = blockIdx.x * 8;
    for (int i = t; i < 8 * NF; i += 256)
        fs2[i / NF][i % NF] = feat[sel_idx[sb + i / NF] * NF + i % NF];
    __syncthreads();
    {   // hidden: 4 outputs/thread (same col; rows r0, r0+2, r0+4, r0+6)
        int col = t & 127, r0 = t >> 7;
        float a0 = b1[col], a1 = a0, a2 = a0, a3 = a0;
        for (int f = 0; f < NF; ++f) {
            float wv = W1[f * DD + col];
            a0 += fs2[r0 + 0][f] * wv;
            a1 += fs2[r0 + 2][f] * wv;
            a2 += fs2[r0 + 4][f] * wv;
            a3 += fs2[r0 + 6][f] * wv;
        }
        hid[r0 + 0][col] = fmaxf(a0, 0.f);
        hid[r0 + 2][col] = fmaxf(a1, 0.f);
        hid[r0 + 4][col] = fmaxf(a2, 0.f);
        hid[r0 + 6][col] = fmaxf(a3, 0.f);
    }
    __syncthreads();
    {   // emb: 4 outputs/thread (same col), W2 row value reused 4x
        int col = t & 127, r0 = t >> 7;
        float a0 = 0.f, a1 = 0.f, a2 = 0.f, a3 = 0.f;
        for (int q = 0; q < DD; ++q) {
            float wv = W2[q * DD + col];
            a0 += hid[r0 + 0][q] * wv;
            a1 += hid[r0 + 2][q] * wv;
            a2 += hid[r0 + 4][q] * wv;
            a3 += hid[r0 + 6][q] * wv;
        }
        float bb = b2[col];
        x8[r0 + 0][col] = a0 + bb;
        x8[r0 + 2][col] = a1 + bb;
        x8[r0 + 4][col] = a2 + bb;
        x8[r0 + 6][col] = a3 + bb;
    }
    __syncthreads();
    for (int jj = t; jj < 512; jj += 256) {
        float base = bih[jj] + bhh[jj];
        float acc[8];
#pragma unroll
        for (int s8 = 0; s8 < 8; ++s8) acc[s8] = base;
        const float4* wr = (const float4*)(Wih + jj * DD);
        for (int q = 0; q < 32; ++q) {
            float4 w4 = wr[q];
#pragma unroll
            for (int s8 = 0; s8 < 8; ++s8) {
                const float4* xs = (const float4*)&x8[s8][0];
                float4 xv = xs[q];
                acc[s8] += w4.x * xv.x + w4.y * xv.y + w4.z * xv.z + w4.w * xv.w;
            }
        }
        int pos = jj & 127, g = jj >> 7;
        for (int s8 = 0; s8 < 8; ++s8) P2[(sb + s8) * 512 + pos * 4 + g] = acc[s8];
    }
}

// ------- sequential LSTM scan (r15 body, equal-best measured) + FUSED k_emb ----
// Blocks 1..625: mask pack AND the full-emb tile compute (bit-identical
// arithmetic to the old k_emb, re-indexed for 512 threads) on the 255 idle
// CUs, hidden under the scan's 360 us shadow. k_emb launch deleted -> scan
// starts ~1 kernel earlier. LDS = 38 KB union (scan 25.6 KB / emb 38.9 KB).
#define LO2(V) __builtin_shufflevector(V, V, 0, 1)
#define HI2(V) __builtin_shufflevector(V, V, 2, 3)
#define MQ(Q) { f32x4 hv = hp[Q]; \
    f32x2 hl = LO2(hv), hh2 = HI2(hv); \
    a0l += LO2(w0##Q) * hl; a0h += HI2(w0##Q) * hh2; \
    a1l += LO2(w1##Q) * hl; a1h += HI2(w1##Q) * hh2; \
    a2l += LO2(w2##Q) * hl; a2h += HI2(w2##Q) * hh2; \
    a3l += LO2(w3##Q) * hl; a3h += HI2(w3##Q) * hh2; }

#define STEP(J, PV) { \
    const f32x4* hp = (const f32x4*)&h_w[w][0]; \
    f32x2 a0l{0,0}, a0h{0,0}, a1l{0,0}, a1h{0,0}, \
          a2l{0,0}, a2h{0,0}, a3l{0,0}, a3h{0,0}; \
    MQ(0) MQ(1) MQ(2) MQ(3) MQ(4) MQ(5) MQ(6) MQ(7) \
    f32x4 ps; \
    ps.x = (a0l.x + a0l.y) + (a0h.x + a0h.y); \
    ps.y = (a1l.x + a1l.y) + (a1h.x + a1h.y); \
    ps.z = (a2l.x + a2l.y) + (a2h.x + a2h.y); \
    ps.w = (a3l.x + a3l.y) + (a3h.x + a3h.y); \
    *(f32x4*)&psum[(J) & 1][kq][gbase] = ps; \
    asm volatile("s_waitcnt lgkmcnt(0)\n\ts_barrier" ::: "memory"); \
    if ((J) == 0 && gh == 1 && g8 > 0) {                 /* bulk H store, prev group */ \
        int pg_ = (g8 - 1) & 1; \
        _Pragma("unroll") \
        for (int u_ = 0; u_ < 2; ++u_) { \
            int jj_ = 2 * (w - 4) + u_, sp_ = (g8 - 1) * 8 + jj_; \
            float2 hv_ = *(const float2*)&h_hist[pg_][jj_][2 * l]; \
            unsigned short ah_ = f2bf(hv_.x), bh_ = f2bf(hv_.y); \
            unsigned short al_ = f2bf(hv_.x - bf2f(ah_)), bl_ = f2bf(hv_.y - bf2f(bh_)); \
            *(unsigned*)&Hhi[sp_ * DD + 2 * l] = (unsigned)ah_ | ((unsigned)bh_ << 16); \
            *(unsigned*)&Hlo[sp_ * DD + 2 * l] = (unsigned)al_ | ((unsigned)bl_ << 16); \
        } \
    } \
    float q00 = psum[(J) & 1][0][t_el],       q01 = psum[(J) & 1][1][t_el]; \
    float q02 = psum[(J) & 1][2][t_el],       q03 = psum[(J) & 1][3][t_el]; \
    float q10 = psum[(J) & 1][0][128 + t_el], q11 = psum[(J) & 1][1][128 + t_el]; \
    float q12 = psum[(J) & 1][2][128 + t_el], q13 = psum[(J) & 1][3][128 + t_el]; \
    float q20 = psum[(J) & 1][0][256 + t_el], q21 = psum[(J) & 1][1][256 + t_el]; \
    float q22 = psum[(J) & 1][2][256 + t_el], q23 = psum[(J) & 1][3][256 + t_el]; \
    float q30 = psum[(J) & 1][0][384 + t_el], q31 = psum[(J) & 1][1][384 + t_el]; \
    float q32 = psum[(J) & 1][2][384 + t_el], q33 = psum[(J) & 1][3][384 + t_el]; \
    float gi = ((q00 + q01) + (q02 + q03)) + (PV).x; \
    float gf = ((q10 + q11) + (q12 + q13)) + (PV).y; \
    float gg = ((q20 + q21) + (q22 + q23)) + (PV).z; \
    float go = ((q30 + q31) + (q32 + q33)) + (PV).w; \
    float ii = sigm(gi), ff = sigm(gf), tg = tanh_fast(gg), oo = sigm(go); \
    c = ff * c + ii * tg; \
    float hh = oo * tanh_fast(c); \
    if (l < 32) { \
        h_w[w][ln] = hh; \
        if (gh == 0) h_hist[(g8 + (((J) == 7) ? 1 : 0)) & 1][((J) + 1) & 7][t_el] = hh; \
    } \
}

#define EMB_FMA4(RR) { f32x4 hvv = *(const f32x4*)&hs[rg * 4 + RR][q]; \
    acc##RR += wv0 * hvv.x + wv1 * hvv.y + wv2 * hvv.z + wv3 * hvv.w; }
#define EMB_ST4(RR) { f32x4 f = acc##RR + bv; us4 hi, lo; \
    hi[0] = f2bf(f.x); lo[0] = f2bf(f.x - bf2f(hi[0])); \
    hi[1] = f2bf(f.y); lo[1] = f2bf(f.y - bf2f(hi[1])); \
    hi[2] = f2bf(f.z); lo[2] = f2bf(f.z - bf2f(hi[2])); \
    hi[3] = f2bf(f.w); lo[3] = f2bf(f.w - bf2f(hi[3])); \
    int row_ = rbase + rg * 4 + RR; \
    *(us4*)&emb_hi[row_ * DD + c4 * 4] = hi; \
    *(us4*)&emb_lo[row_ * DD + c4 * 4] = lo; }

__global__ __launch_bounds__(512, 1) void k_lstm(const float* __restrict__ W2T,
                                                 const float* __restrict__ P2,
                                                 const float* __restrict__ init_h,
                                                 const float* __restrict__ init_c,
                                                 unsigned short* __restrict__ Hhi,
                                                 unsigned short* __restrict__ Hlo,
                                                 const int* __restrict__ sel,
                                                 const int* __restrict__ good,
                                                 unsigned long long* __restrict__ selw,
                                                 unsigned long long* __restrict__ goodw,
                                                 const float* __restrict__ feat,
                                                 const float* __restrict__ W1,
                                                 const float* __restrict__ b1,
                                                 const float* __restrict__ W2,
                                                 const float* __restrict__ b2,
                                                 unsigned short* __restrict__ emb_hi,
                                                 unsigned short* __restrict__ emb_lo) {
    __shared__ __align__(16) char smem[38912];        // union: scan 25.6K / emb 38.9K

    if (blockIdx.x != 0) {
        // ---- mask pack: ballot -> u64 words, TRANSPOSED layout [b][s] ----
        int t = threadIdx.x;
        int wave = ((blockIdx.x - 1) * 512 + t) >> 6;   // 0..4999
        int lane = t & 63;
        for (int i = 0; i < 64; ++i) {
            int chunk = wave * 64 + i;                  // 0..319999
            int s = chunk / NW;
            int b = chunk - s * NW;
            int idx = s * N_CL + b * 64 + lane;
            unsigned long long bs = __ballot(sel[idx]  != 0);
            unsigned long long bg = __ballot(good[idx] != 0);
            if (lane == 0) { selw[b * SS + s] = bs; goodw[b * SS + s] = bg; }
        }
        // ---- fused k_emb tile: rows (blockIdx.x-1)*64 .. +63 ----
        float (*fs)[NF]  = (float (*)[NF])smem;
        float (*hs)[132] = (float (*)[132])(smem + 5120);
        int rbase = (blockIdx.x - 1) * 64;
        for (int i = t; i < 64 * NF; i += 512)
            fs[i / NF][i % NF] = feat[rbase * NF + i];
        __syncthreads();
        {   // hidden: same per-(r,c) arithmetic as old k_emb
            int cc = t & 127;
            float bb = b1[cc];
#pragma unroll
            for (int k = 0; k < 16; ++k) {
                int r = (t >> 7) + 4 * k;
                float acc = bb;
#pragma unroll
                for (int f = 0; f < NF; ++f) acc += fs[r][f] * W1[f * DD + cc];
                hs[r][cc] = fmaxf(acc, 0.f);
            }
        }
        __syncthreads();
        int c4 = t & 31, rg = t >> 5;                  // rg 0..15, 4 rows each
        f32x4 acc0{0,0,0,0}, acc1{0,0,0,0}, acc2{0,0,0,0}, acc3{0,0,0,0};
        for (int q = 0; q < DD; q += 4) {
            f32x4 wv0 = *(const f32x4*)&W2[(q + 0) * DD + c4 * 4];
            f32x4 wv1 = *(const f32x4*)&W2[(q + 1) * DD + c4 * 4];
            f32x4 wv2 = *(const f32x4*)&W2[(q + 2) * DD + c4 * 4];
            f32x4 wv3 = *(const f32x4*)&W2[(q + 3) * DD + c4 * 4];
            EMB_FMA4(0) EMB_FMA4(1) EMB_FMA4(2) EMB_FMA4(3)
        }
        f32x4 bv = *(const f32x4*)&b2[c4 * 4];
        EMB_ST4(0) EMB_ST4(1) EMB_ST4(2) EMB_ST4(3)
        return;
    }

    float (*psum)[4][512]  = (float (*)[4][512])smem;           // [2][4][512]
    float (*h_w)[32]       = (float (*)[32])(smem + 16384);     // [8][32]
    float (*h_hist)[8][128]= (float (*)[8][128])(smem + 17408); // [2][8][128]

    int t = threadIdx.x, w = t >> 6, l = t & 63;
    int kq = w & 3, gh = w >> 2, ln = l & 31;
    int gbase = gh * 256 + l * 4;
    int t_el = kq * 32 + ln;

    // coalesced weight base: wave w, lane l; instruction i at wT[i*64]
    const f32x4* wT = (const f32x4*)W2T + (size_t)w * 2048 + l;
    f32x4 w00 = wT[ 0 * 64], w01 = wT[ 1 * 64], w02 = wT[ 2 * 64], w03 = wT[ 3 * 64],
          w04 = wT[ 4 * 64], w05 = wT[ 5 * 64], w06 = wT[ 6 * 64], w07 = wT[ 7 * 64];
    f32x4 w10 = wT[ 8 * 64], w11 = wT[ 9 * 64], w12 = wT[10 * 64], w13 = wT[11 * 64],
          w14 = wT[12 * 64], w15 = wT[13 * 64], w16 = wT[14 * 64], w17 = wT[15 * 64];
    f32x4 w20 = wT[16 * 64], w21 = wT[17 * 64], w22 = wT[18 * 64], w23 = wT[19 * 64],
          w24 = wT[20 * 64], w25 = wT[21 * 64], w26 = wT[22 * 64], w27 = wT[23 * 64];
    f32x4 w30 = wT[24 * 64], w31 = wT[25 * 64], w32 = wT[26 * 64], w33 = wT[27 * 64],
          w34 = wT[28 * 64], w35 = wT[29 * 64], w36 = wT[30 * 64], w37 = wT[31 * 64];

    float c = init_c[t_el];                           // dup across lane halves
    if (l < 32) {
        float h0 = init_h[t_el];
        h_w[w][ln] = h0;
        if (gh == 0) h_hist[0][0][t_el] = h0;         // h input of step 0
    }
    asm volatile("s_waitcnt lgkmcnt(0)\n\ts_barrier" ::: "memory");

    for (int g8 = 0; g8 < 64; ++g8) {
        const float* pb = P2 + g8 * 4096 + t_el * 4;  // this thread's gate slice
        f32x4 pv0 = *(const f32x4*)(pb + 0 * 512);
        f32x4 pv1 = *(const f32x4*)(pb + 1 * 512);
        f32x4 pv2 = *(const f32x4*)(pb + 2 * 512);
        f32x4 pv3 = *(const f32x4*)(pb + 3 * 512);
        STEP(0, pv0) STEP(1, pv1) STEP(2, pv2) STEP(3, pv3)
        f32x4 pv4 = *(const f32x4*)(pb + 4 * 512);
        f32x4 pv5 = *(const f32x4*)(pb + 5 * 512);
        f32x4 pv6 = *(const f32x4*)(pb + 6 * 512);
        f32x4 pv7 = *(const f32x4*)(pb + 7 * 512);
        STEP(4, pv4) STEP(5, pv5) STEP(6, pv6) STEP(7, pv7)
    }

    // tail: store group 63's H (steps 504..511), parity 1
    asm volatile("s_waitcnt lgkmcnt(0)\n\ts_barrier" ::: "memory");
    if (gh == 1) {
#pragma unroll
        for (int u = 0; u < 2; ++u) {
            int jj = 2 * (w - 4) + u, sp = 504 + jj;
            float2 hv = *(const float2*)&h_hist[1][jj][2 * l];
            unsigned short ah = f2bf(hv.x), bh = f2bf(hv.y);
            unsigned short al = f2bf(hv.x - bf2f(ah)), bl = f2bf(hv.y - bf2f(bh));
            *(unsigned*)&Hhi[sp * DD + 2 * l] = (unsigned)ah | ((unsigned)bh << 16);
            *(unsigned*)&Hlo[sp * DD + 2 * l] = (unsigned)al | ((unsigned)bl << 16);
        }
    }
}

// ------- phase C: MFMA GEMM logits, SINGLE PASS over all 512 steps -------------
__global__ __launch_bounds__(256, 1) void k_logits(
        const unsigned short* __restrict__ emb_hi,
        const unsigned short* __restrict__ emb_lo,
        const unsigned short* __restrict__ Hhi,
        const unsigned short* __restrict__ Hlo,
        const unsigned long long* __restrict__ selw,
        const unsigned long long* __restrict__ goodw,
        float* __restrict__ part) {
    int b = blockIdx.x;
    int t = threadIdx.x, wv = t >> 6, l = t & 63;
    int ln = l & 31, lh = l >> 5;
    int rb = b * 64;
    const short8* A0h = (const short8*)(emb_hi + (rb + ln) * DD + lh * 8);
    const short8* A0l = (const short8*)(emb_lo + (rb + ln) * DD + lh * 8);
    const short8* A1h = (const short8*)(emb_hi + (rb + 32 + ln) * DD + lh * 8);
    const short8* A1l = (const short8*)(emb_lo + (rb + 32 + ln) * DD + lh * 8);
    for (int sg = 0; sg < 4; ++sg) {
        int s0 = sg * 128 + wv * 32;
        const short8* Bhp = (const short8*)(Hhi + (s0 + ln) * DD + lh * 8);
        const short8* Blp = (const short8*)(Hlo + (s0 + ln) * DD + lh * 8);
        f32x16 acc0, acc1;
#pragma unroll
        for (int r = 0; r < 16; ++r) { acc0[r] = 0.f; acc1[r] = 0.f; }
#pragma unroll
        for (int kc = 0; kc < 8; ++kc) {           // K = 8 x 16
            short8 a0h = A0h[kc * 2], a0l = A0l[kc * 2];
            short8 a1h = A1h[kc * 2], a1l = A1l[kc * 2];
            short8 bh = Bhp[kc * 2], bl = Blp[kc * 2];
            acc0 = __builtin_amdgcn_mfma_f32_32x32x16_bf16(a0h, bh, acc0, 0, 0, 0);
            acc0 = __builtin_amdgcn_mfma_f32_32x32x16_bf16(a0l, bh, acc0, 0, 0, 0);
            acc0 = __builtin_amdgcn_mfma_f32_32x32x16_bf16(a0h, bl, acc0, 0, 0, 0);
            acc1 = __builtin_amdgcn_mfma_f32_32x32x16_bf16(a1h, bh, acc1, 0, 0, 0);
            acc1 = __builtin_amdgcn_mfma_f32_32x32x16_bf16(a1l, bh, acc1, 0, 0, 0);
            acc1 = __builtin_amdgcn_mfma_f32_32x32x16_bf16(a1h, bl, acc1, 0, 0, 0);
        }
        int s = s0 + ln;
        unsigned long long sw = selw[b * SS + s];  // coalesced, [b][s] layout
        unsigned long long gw = goodw[b * SS + s];
        float m = NEGF;
#pragma unroll
        for (int r = 0; r < 16; ++r) {
            int row = (r & 3) + 8 * (r >> 2) + 4 * lh;
            float v0 = acc0[r], v1 = acc1[r];
            m = fmaxf(m, ((sw >> row) & 1ull) ? v0 : NEGF);
            m = fmaxf(m, ((sw >> (row + 32)) & 1ull) ? v1 : NEGF);
        }
        m = fmaxf(m, __shfl_xor(m, 32));
        float se = 0.f, sl = 0.f, slg = 0.f;
#pragma unroll
        for (int r = 0; r < 16; ++r) {
            int row = (r & 3) + 8 * (r >> 2) + 4 * lh;
            float v0 = acc0[r], v1 = acc1[r];
            float e0 = ((sw >> row) & 1ull) ? __expf(v0 - m) : 0.f;
            float e1 = ((sw >> (row + 32)) & 1ull) ? __expf(v1 - m) : 0.f;
            se += e0 + e1;
            sl += e0 * v0 + e1 * v1;
            slg += (((gw >> row) & 1ull) ? v0 : 0.f)
                 + (((gw >> (row + 32)) & 1ull) ? v1 : 0.f);
        }
        se += __shfl_xor(se, 32);
        sl += __shfl_xor(sl, 32);
        slg += __shfl_xor(slg, 32);
        if (lh == 0) {
            int o = s * NW + b;                    // TRANSPOSED part: [s][b]
            part[0 * PARTN + o] = m;
            part[1 * PARTN + o] = se;
            part[2 * PARTN + o] = sl;
            part[3 * PARTN + o] = slg;
            part[4 * PARTN + o] = (float)__popcll(sw);
            part[5 * PARTN + o] = (float)__popcll(gw);
        }
    }
}

// ------- per-step merge of 625 block partials (coalesced [s][b] reads) ---------
__global__ __launch_bounds__(64) void k_reduce(const float* __restrict__ part,
                                               float* __restrict__ Aout,
                                               float* __restrict__ Bout,
                                               float* __restrict__ actout) {
    int s = blockIdx.x;
    int t = threadIdx.x;     // 64 threads, one wave
    float m = NEGF, se = 0.f, sl = 0.f, slg = 0.f, np = 0.f, ng = 0.f;
    for (int b = t; b < NW; b += 64) {
        int o = s * NW + b;                        // lanes consecutive
        float m2  = part[0 * PARTN + o];
        float se2 = part[1 * PARTN + o];
        float sl2 = part[2 * PARTN + o];
        slg += part[3 * PARTN + o];
        np  += part[4 * PARTN + o];
        ng  += part[5 * PARTN + o];
        float nm = fmaxf(m, m2);
        float a = __expf(m - nm), a2 = __expf(m2 - nm);
        se = se * a + se2 * a2;
        sl = sl * a + sl2 * a2;
        m = nm;
    }
    for (int off = 32; off > 0; off >>= 1) {
        float m2  = __shfl_xor(m, off);
        float se2 = __shfl_xor(se, off);
        float sl2 = __shfl_xor(sl, off);
        slg += __shfl_xor(slg, off);
        np  += __shfl_xor(np, off);
        ng  += __shfl_xor(ng, off);
        float nm = fmaxf(m, m2);
        float a = __expf(m - nm), a2 = __expf(m2 - nm);
        se = se * a + se2 * a2;
        sl = sl * a + sl2 * a2;
        m = nm;
    }
    if (t == 0) {
        float lse = m + logf(se);
        float nbad = np - ng;
        int active = (ng > 0.5f) && (nbad > 0.5f);
        float ce = (ng * lse - slg) / fmaxf(ng, 1.f);
        float A = (nbad / fmaxf(np, 1.f)) * ce;
        float minus_ent = sl / se - lse;
        float B = ECOEF * (minus_ent / logf(fmaxf(np, 2.0f)));
        Aout[s] = A; Bout[s] = B; actout[s] = active ? 1.f : 0.f;
    }
}

// ---------------- exact sequential discount prefix + final sum -----------------
__global__ __launch_bounds__(64) void k_final(const float* __restrict__ A,
                                              const float* __restrict__ B,
                                              const float* __restrict__ act,
                                              float* __restrict__ out) {
    int lane = threadIdx.x;
    float loss = 0.f;
    int base = 0;
    for (int ch = 0; ch < 8; ++ch) {
        int s = ch * 64 + lane;
        bool a = act[s] > 0.5f;
        unsigned long long bal = __ballot(a);
        unsigned long long ltmask = (lane == 0) ? 0ull : (~0ull >> (64 - lane));
        int pre = __popcll(bal & ltmask);
        if (a) {
            float f = powf(DISCOUNT, (float)(base + pre));
            loss += f * A[s] + B[s];
        }
        base += __popcll(bal);
    }
    for (int off = 32; off > 0; off >>= 1) loss += __shfl_xor(loss, off);
    if (lane == 0) out[0] = loss / fmaxf((float)base, 1.f);
}

extern "C" void kernel_launch(void* const* d_in, const int* in_sizes, int n_in,
                              void* d_out, int out_size, void* d_ws, size_t ws_size,
                              hipStream_t stream) {
    (void)in_sizes; (void)n_in; (void)out_size; (void)ws_size;
    const float* feat    = (const float*)d_in[0];
    const int*   sel     = (const int*)d_in[1];
    const int*   good    = (const int*)d_in[2];
    const int*   sel_idx = (const int*)d_in[3];
    const float* W1      = (const float*)d_in[4];
    const float* b1      = (const float*)d_in[5];
    const float* W2      = (const float*)d_in[6];
    const float* b2      = (const float*)d_in[7];
    const float* init_h  = (const float*)d_in[8];
    const float* init_c  = (const float*)d_in[9];
    const float* Wih     = (const float*)d_in[10];
    const float* Whh     = (const float*)d_in[11];
    const float* bih     = (const float*)d_in[12];
    const float* bhh     = (const float*)d_in[13];
    float* out = (float*)d_out;
    char* ws = (char*)d_ws;

    float*          W2T    = (float*)(ws + 0);                    //  1,048,576 B
    unsigned short* emb_hi = (unsigned short*)(ws + 20480000);    // 10,240,000 B
    unsigned short* emb_lo = (unsigned short*)(ws + 30720000);    // 10,240,000 B
    float*          P2     = (float*)(ws + 40960000);             //  1,048,576 B
    unsigned short* Hhi    = (unsigned short*)(ws + 42008576);    //    131,072 B
    unsigned short* Hlo    = (unsigned short*)(ws + 42139648);    //    131,072 B
    unsigned long long* selw  = (unsigned long long*)(ws + 42270720);  // 2,560,000 B
    unsigned long long* goodw = (unsigned long long*)(ws + 44830720);  // 2,560,000 B
    float*          part   = (float*)(ws + 47390720);             //  7,680,000 B
    float*          Aarr   = (float*)(ws + 55070720);             //      2,048 B
    float*          Barr   = (float*)(ws + 55072768);             //      2,048 B
    float*          actarr = (float*)(ws + 55074816);             //      2,048 B

    // k_pgemm is now self-contained (computes its own 512-row embeddings) ->
    // k_emb is OFF the critical path, fused into k_lstm's shadow blocks.
    k_pgemm <<<96, 256, 0, stream>>>(feat, W1, b1, W2, b2, sel_idx,
                                     Wih, bih, bhh, Whh, W2T, P2);
    k_lstm  <<<626, 512, 0, stream>>>(W2T, P2, init_h, init_c, Hhi, Hlo,
                                      sel, good, selw, goodw,
                                      feat, W1, b1, W2, b2, emb_hi, emb_lo);
    k_logits<<<NW, 256, 0, stream>>>(emb_hi, emb_lo, Hhi, Hlo, selw, goodw, part);
    k_reduce<<<SS, 64, 0, stream>>>(part, Aarr, Barr, actarr);
    k_final <<<1, 64, 0, stream>>>(Aarr, Barr, actarr, out);
}